// Round 8
// baseline (341.366 us; speedup 1.0000x reference)
//
#include <hip/hip_runtime.h>
#include <hip/hip_bf16.h>
#include <stdint.h>

#define N_TOK 16384
#define D_IN  2048
#define D_HID 2048

typedef __attribute__((ext_vector_type(8))) short  bf16x8;
typedef __attribute__((ext_vector_type(4))) float  f32x4;
typedef __attribute__((ext_vector_type(8))) unsigned short u16x8;

__device__ __forceinline__ unsigned short f2bf(float f) {
    unsigned int u = __float_as_uint(f);
    u = (u + 0x7FFFu + ((u >> 16) & 1u)) >> 16;
    return (unsigned short)u;
}

// ---------------------------------------------------------------- gate ----
__global__ void gate_kernel(const float* __restrict__ x,
                            const float* __restrict__ Wg,
                            const float* __restrict__ bg,
                            float* __restrict__ s12,
                            int* __restrict__ eidx) {
    const int token = blockIdx.x * 4 + (threadIdx.x >> 6);
    const int lane  = threadIdx.x & 63;
    const float* xr = x + (size_t)token * D_IN;

    float acc[8];
#pragma unroll
    for (int e = 0; e < 8; ++e) acc[e] = 0.f;

    for (int i = lane; i < D_IN; i += 64) {
        float xv = xr[i];
        const float4* wr = (const float4*)(Wg + (size_t)i * 8);
        float4 w0 = wr[0], w1 = wr[1];
        acc[0] += xv * w0.x; acc[1] += xv * w0.y;
        acc[2] += xv * w0.z; acc[3] += xv * w0.w;
        acc[4] += xv * w1.x; acc[5] += xv * w1.y;
        acc[6] += xv * w1.z; acc[7] += xv * w1.w;
    }
#pragma unroll
    for (int off = 32; off > 0; off >>= 1) {
#pragma unroll
        for (int e = 0; e < 8; ++e) acc[e] += __shfl_xor(acc[e], off);
    }

    float lg[8];
    float mx = -1e30f;
#pragma unroll
    for (int e = 0; e < 8; ++e) { lg[e] = acc[e] + bg[e]; mx = fmaxf(mx, lg[e]); }
    float sum = 0.f;
#pragma unroll
    for (int e = 0; e < 8; ++e) { lg[e] = expf(lg[e] - mx); sum += lg[e]; }
    float inv = 1.f / sum;

    float s1 = -1.f, s2 = -1.f; int i1 = 0, i2 = 0;
#pragma unroll
    for (int e = 0; e < 8; ++e) {
        float g = lg[e] * inv;
        if (g > s1)      { s2 = s1; i2 = i1; s1 = g; i1 = e; }
        else if (g > s2) { s2 = g;  i2 = e; }
    }
    if (lane == 0) {
        s12[token * 2]     = s1;
        s12[token * 2 + 1] = s2;
        if (token == 0) { eidx[0] = i1; eidx[1] = i2; }
    }
}

// ------------------------------- x -> bf16, slab order (staging image) ----
__global__ __launch_bounds__(256) void xconv_kernel(
    const float* __restrict__ x, unsigned short* __restrict__ xb) {
    const int mt = blockIdx.x >> 6;
    const int kt = blockIdx.x & 63;
    const int t  = threadIdx.x;
    const float* src = x + ((size_t)(mt * 256 + t)) * D_IN + kt * 32;
    unsigned short* slab = xb + ((size_t)(mt * 64 + kt)) * 8192;
#pragma unroll
    for (int ks = 0; ks < 4; ++ks) {
        float4 a = *(const float4*)(src + ks * 8);
        float4 b = *(const float4*)(src + ks * 8 + 4);
        u16x8 v;
        v[0] = f2bf(a.x); v[1] = f2bf(a.y); v[2] = f2bf(a.z); v[3] = f2bf(a.w);
        v[4] = f2bf(b.x); v[5] = f2bf(b.y); v[6] = f2bf(b.z); v[7] = f2bf(b.w);
        *(u16x8*)(slab + (ks * 256 + t) * 8) = v;
    }
}

// --------------------- W[e0],W[e1] -> bf16 slab order (transposed) --------
__global__ void wconv_kernel(const float* __restrict__ W,
                             const int* __restrict__ eidx,
                             unsigned short* __restrict__ wbT) {
    __shared__ float tile[64][65];
    const int be  = blockIdx.z;
    const int e   = eidx[be];
    const int k0  = blockIdx.y * 64;
    const int n0  = blockIdx.x * 64;
    const int bx  = n0 >> 7;
    const int cl0 = n0 & 127;
    const int kt0 = k0 >> 5;
    const float* src = W + (size_t)e * D_IN * D_HID;
    const int t = threadIdx.x;

#pragma unroll
    for (int p = 0; p < 4; ++p) {
        int row = p * 16 + (t >> 4);
        int col = (t & 15) * 4;
        const float* s = src + (size_t)(k0 + row) * D_HID + n0 + col;
        tile[row][col]     = s[0];
        tile[row][col + 1] = s[1];
        tile[row][col + 2] = s[2];
        tile[row][col + 3] = s[3];
    }
    __syncthreads();

    const int g   = (t >> 5) * 8;
    const int ktl = t >> 7;
    const int ks  = (t >> 5) & 3;
#pragma unroll
    for (int p = 0; p < 2; ++p) {
        int n = p * 32 + (t & 31);
        u16x8 v;
#pragma unroll
        for (int j = 0; j < 8; ++j) v[j] = f2bf(tile[g + j][n]);
        unsigned short* dst = wbT + ((size_t)(bx * 64 + kt0 + ktl)) * 8192 +
                              ((size_t)(ks * 256 + be * 128 + cl0 + n)) * 8;
        *(u16x8*)dst = v;
    }
}

// ------------------------------------------------------------------ GEMM --
// m201-class 8-phase schedule: BK=64, 2 LDS buffers x 2 K-halves (128 KiB),
// 4 phases per K-tile, each {ds_read 4-8 b128 | 2 gload_lds | [vmcnt] |
// BAR | lgkm0 | sched_barrier | setprio1 | 16 MFMA | setprio0 | BAR}.
// vmcnt(4) at p1 (retires tH1, needed p2) and p3 (retires t+1 H0, needed
// next tile) -- never drains; ~3-phase prefetch lead. Slab sources keep
// every gload_lds wave-contiguous; LDS image = slab image (0-conflict).
#define GLD16(gp, lp)                                                        \
    __builtin_amdgcn_global_load_lds(                                        \
        (const __attribute__((address_space(1))) void*)(gp),                 \
        (__attribute__((address_space(3))) void*)(lp), 16, 0, 0)

#define LDSV(SLOT) (*(const bf16x8*)&lds[(SLOT) * 8])

// phase P of tile (buffer CB): mh=P&1 (row half), kk=P>>1 (K half)
#define PHASE(CB, P, T1, DOSTAGE, VMSTR)                                     \
    do {                                                                     \
        const int hb = (CB) * 4096 + ((P) >> 1) * 2048;                      \
        if (((P) & 1) == 0) {                                                \
            bC[0] = LDSV(hb + 1024 + bro);                                   \
            bC[1] = LDSV(hb + 1024 + bro + 16);                              \
            bC[2] = LDSV(hb + 1024 + bro + 32);                              \
            bC[3] = LDSV(hb + 1024 + bro + 48);                              \
        }                                                                    \
        aP[0] = LDSV(hb + aro + ((P) & 1) * 64);                             \
        aP[1] = LDSV(hb + aro + ((P) & 1) * 64 + 16);                        \
        aP[2] = LDSV(hb + aro + ((P) & 1) * 64 + 32);                        \
        aP[3] = LDSV(hb + aro + ((P) & 1) * 64 + 48);                        \
        if (DOSTAGE) {                                                       \
            const size_t so = ((size_t)(2 * (T1) + ((P) >> 1)) * 1024 +      \
                               ((P) & 1) * 512) * 8;                         \
            const int dd = ((CB) ^ 1) * 4096 + ((P) >> 1) * 2048 +           \
                           ((P) & 1) * 512 + t512;                           \
            GLD16(gA0 + so, &lds[dd * 8]);                                   \
            GLD16(gB0 + so, &lds[(dd + 1024) * 8]);                          \
        }                                                                    \
        if (VMSTR[0]) asm volatile(VMSTR ::: "memory");                      \
        __builtin_amdgcn_s_barrier();                                        \
        asm volatile("s_waitcnt lgkmcnt(0)" ::: "memory");                   \
        __builtin_amdgcn_sched_barrier(0);                                   \
        __builtin_amdgcn_s_setprio(1);                                       \
        _Pragma("unroll")                                                    \
        for (int mi = 0; mi < 4; ++mi)                                       \
            _Pragma("unroll")                                                \
            for (int ni = 0; ni < 4; ++ni)                                   \
                acc[((P) & 1) * 4 + mi][ni] =                                \
                    __builtin_amdgcn_mfma_f32_16x16x32_bf16(                 \
                        aP[mi], bC[ni], acc[((P) & 1) * 4 + mi][ni], 0, 0, 0); \
        __builtin_amdgcn_s_setprio(0);                                       \
        __builtin_amdgcn_s_barrier();                                        \
    } while (0)

__global__ __launch_bounds__(512, 2) void moe_gemm_kernel(
    const unsigned short* __restrict__ xb,   // slab order [mt64][kt64][1024]
    const unsigned short* __restrict__ wbT,  // slab order [bx16][kt64][1024]
    const float* __restrict__ b_exp,         // [8][D_HID]
    const int* __restrict__ eidx,
    const float* __restrict__ s12,           // [N_TOK][2]
    float* __restrict__ out) {
    // 2 buffers x (2 halves x (A 1024 + B 1024 granules)) x 16B = 128 KiB
    __shared__ __align__(16) short lds[2 * 4096 * 8];

    const int t512 = threadIdx.x;
    const int lane = t512 & 63;
    const int w    = t512 >> 6;
    const int wm   = w >> 2;
    const int wn   = w & 3;

    // XCD swizzle: each XCD owns a bx pair (B slabs 2 MB -> L2-resident)
    const int bid = blockIdx.x;
    const int xcd = bid & 7;
    const int jb  = bid >> 3;
    const int bx  = xcd * 2 + (jb & 1);
    const int by  = jb >> 1;
    const int mbase = by * 256;
    const int nbase = bx * 128;

    const unsigned short* gA0 = xb  + ((size_t)by * 64) * 8192 + t512 * 8;
    const unsigned short* gB0 = wbT + ((size_t)bx * 64) * 8192 + t512 * 8;

    // ds_read bases (granule units within a half)
    const int aro = (lane >> 4) * 256 + wm * 128 + (lane & 15);
    const int bro = (lane >> 4) * 256 + wn * 64 + (lane & 15);

    f32x4 acc[8][4];
#pragma unroll
    for (int mi = 0; mi < 8; ++mi)
#pragma unroll
        for (int ni = 0; ni < 4; ++ni) acc[mi][ni] = (f32x4){0.f, 0.f, 0.f, 0.f};

    bf16x8 aP[4], bC[4];

    // prologue: stage tile 0 into buffer 0 (8 loads); vmcnt(4) -> H0 ready.
#pragma unroll
    for (int p = 0; p < 4; ++p) {
        const size_t so = ((size_t)(p >> 1) * 1024 + (p & 1) * 512) * 8;
        const int dd = (p >> 1) * 2048 + (p & 1) * 512 + t512;
        GLD16(gA0 + so, &lds[dd * 8]);
        GLD16(gB0 + so, &lds[(dd + 1024) * 8]);
    }
    asm volatile("s_waitcnt vmcnt(4)" ::: "memory");
    __builtin_amdgcn_s_barrier();

    int cb = 0;
    for (int t = 0; t < 31; ++t) {
        PHASE(cb, 0, t + 1, 1, "");
        PHASE(cb, 1, t + 1, 1, "s_waitcnt vmcnt(4)");
        PHASE(cb, 2, t + 1, 1, "");
        PHASE(cb, 3, t + 1, 1, "s_waitcnt vmcnt(4)");
        cb ^= 1;
    }
    // tile 31 (buffer 1): no staging; drain H1 at p1.
    PHASE(1, 0, 0, 0, "");
    PHASE(1, 1, 0, 0, "s_waitcnt vmcnt(0)");
    PHASE(1, 2, 0, 0, "");
    PHASE(1, 3, 0, 0, "");

    // -------- epilogue: combine experts through LDS (f32) --------
    __syncthreads();
    float* fl = (float*)lds;
    if (wn >= 2) {
        float* reg = fl + (wm * 2 + (wn - 2)) * 8192;   // [128][64]
#pragma unroll
        for (int mi = 0; mi < 8; ++mi)
#pragma unroll
            for (int ni = 0; ni < 4; ++ni)
#pragma unroll
                for (int j = 0; j < 4; ++j) {
                    int row_l = mi * 16 + ((lane >> 4) << 2) + j;
                    int col_l = ni * 16 + (lane & 15);
                    reg[row_l * 64 + col_l] = acc[mi][ni][j];
                }
    }
    __syncthreads();
    if (wn < 2) {
        const float* reg = fl + (wm * 2 + wn) * 8192;
        const int e0 = eidx[0], e1 = eidx[1];
        const float* bb0 = b_exp + (size_t)e0 * D_HID;
        const float* bb1 = b_exp + (size_t)e1 * D_HID;
        const float2* s12v = (const float2*)s12;
        int   cc[4];
        float b0c[4], b1c[4];
#pragma unroll
        for (int ni = 0; ni < 4; ++ni) {
            cc[ni]  = nbase + wn * 64 + ni * 16 + (lane & 15);
            b0c[ni] = bb0[cc[ni]];
            b1c[ni] = bb1[cc[ni]];
        }
#pragma unroll
        for (int mi = 0; mi < 8; ++mi)
#pragma unroll
            for (int j = 0; j < 4; ++j) {
                int row_l = mi * 16 + ((lane >> 4) << 2) + j;
                int r = mbase + wm * 128 + row_l;
                float2 s = s12v[r];
#pragma unroll
                for (int ni = 0; ni < 4; ++ni) {
                    float y1 = reg[row_l * 64 + ni * 16 + (lane & 15)];
                    out[(size_t)r * D_HID + cc[ni]] =
                        s.x * (acc[mi][ni][j] + b0c[ni]) + s.y * (y1 + b1c[ni]);
                }
            }
    }
}

// ---------------------------------------------------------------- launch --
extern "C" void kernel_launch(void* const* d_in, const int* in_sizes, int n_in,
                              void* d_out, int out_size, void* d_ws, size_t ws_size,
                              hipStream_t stream) {
    const float* x         = (const float*)d_in[0];
    const float* W_experts = (const float*)d_in[1];
    const float* b_experts = (const float*)d_in[2];
    const float* W_gate    = (const float*)d_in[3];
    const float* b_gate    = (const float*)d_in[4];
    float* out = (float*)d_out;

    char* ws = (char*)d_ws;
    float* s12  = (float*)ws;                                        // 128 KiB
    int*   eidx = (int*)(ws + 131072);
    unsigned short* xb  = (unsigned short*)(ws + 262144);            // 64 MiB
    unsigned short* wbT = (unsigned short*)(ws + 262144 + 67108864); // 16 MiB

    gate_kernel<<<N_TOK / 4, 256, 0, stream>>>(x, W_gate, b_gate, s12, eidx);
    xconv_kernel<<<4096, 256, 0, stream>>>(x, xb);
    wconv_kernel<<<dim3(32, 32, 2), 256, 0, stream>>>(W_experts, eidx, wbT);
    moe_gemm_kernel<<<1024, 512, 0, stream>>>(xb, wbT, b_experts, eidx, s12, out);
}